// Round 1
// baseline (303.417 us; speedup 1.0000x reference)
//
#include <hip/hip_runtime.h>
#include <hip/hip_bf16.h>
#include <cstdint>

typedef __bf16 bf16x8 __attribute__((ext_vector_type(8)));
typedef float f32x4 __attribute__((ext_vector_type(4)));

// ---------------- async global->LDS (16B per lane) ----------------
__device__ __forceinline__ void gld16(const void* g, void* lds) {
    __builtin_amdgcn_global_load_lds(
        (__attribute__((address_space(1))) void*)(uintptr_t)g,
        (__attribute__((address_space(3))) void*)(uint32_t)(uintptr_t)lds,
        16, 0, 0);
}

// ---------------- transpose + f32->bf16 convert: out[C][R] = in[R][C] ----------------
__global__ __launch_bounds__(256) void transpose_bf16_k(const float* __restrict__ in,
                                                        __bf16* __restrict__ out,
                                                        int R, int C) {
    __shared__ float t[64][65];
    const int r0 = blockIdx.x * 64, c0 = blockIdx.y * 64;
    const int tid = threadIdx.x;
#pragma unroll
    for (int i = 0; i < 16; i++) {
        int idx = i * 256 + tid;
        int rr = idx >> 6, cc = idx & 63;
        t[rr][cc] = in[(size_t)(r0 + rr) * C + (c0 + cc)];
    }
    __syncthreads();
#pragma unroll
    for (int i = 0; i < 16; i++) {
        int idx = i * 256 + tid;
        int rr = idx >> 6, cc = idx & 63;  // rr -> out row (col of in), cc -> out col (row of in)
        out[(size_t)(c0 + rr) * R + (r0 + cc)] = (__bf16)t[cc][rr];
    }
}

// ---------------- encoder: per (row, segment) 2-layer MLP ----------------
// MODE 0: prop (DIN=5: obs[2k],obs[2k+1],act[0..2]); MODE 1/2: contiguous DIN floats at xBase+DIN*k
template <int DIN, int MODE>
__global__ __launch_bounds__(256) void enc_kernel(const float* __restrict__ obs,
                                                  const float* __restrict__ act,
                                                  const float* __restrict__ W1g,
                                                  const float* __restrict__ b1g,
                                                  const float* __restrict__ W2g,
                                                  const float* __restrict__ b2g,
                                                  __bf16* __restrict__ enc,
                                                  int kgBase, int xBase) {
    const int k = blockIdx.y;
    const int kg = kgBase + k;
    __shared__ float sW1[DIN * 32];
    __shared__ float sW2[32 * 64];
    __shared__ float sb1[32];
    __shared__ float sb2[64];
    const int tid = threadIdx.x;
    for (int i = tid; i < DIN * 32; i += 256) sW1[i] = W1g[k * DIN * 32 + i];
    for (int i = tid; i < 2048; i += 256) sW2[i] = W2g[k * 2048 + i];
    if (tid < 32) sb1[tid] = b1g[k * 32 + tid];
    else if (tid < 96) sb2[tid - 32] = b2g[k * 64 + (tid - 32)];
    __syncthreads();

    const int r = blockIdx.x * 256 + tid;  // 0..49151  (= b*3+p)
    const float* orow = obs + (size_t)r * 144;
    float x[DIN];
    if (MODE == 0) {
        x[0] = orow[2 * k];
        x[1] = orow[2 * k + 1];
        const float* arow = act + (size_t)r * 3;
        x[2] = arow[0]; x[3] = arow[1]; x[4] = arow[2];
    } else {
#pragma unroll
        for (int i = 0; i < DIN; i++) x[i] = orow[xBase + DIN * k + i];
    }

    float h[32];
#pragma unroll
    for (int o = 0; o < 32; o++) {
        float a = sb1[o];
#pragma unroll
        for (int i = 0; i < DIN; i++) a += x[i] * sW1[i * 32 + o];
        h[o] = fmaxf(a, 0.01f * a);  // leaky relu
    }

    __bf16* dst = enc + (size_t)r * 896 + kg * 64;
#pragma unroll
    for (int og = 0; og < 8; og++) {
        bf16x8 tmp;
#pragma unroll
        for (int oi = 0; oi < 8; oi++) {
            const int o = og * 8 + oi;
            float a = sb2[o];
#pragma unroll
            for (int hh = 0; hh < 32; hh++) a += h[hh] * sW2[hh * 64 + o];
            a = fmaxf(a, 0.01f * a);
            tmp[oi] = (__bf16)a;
        }
        *(bf16x8*)&dst[og * 8] = tmp;
    }
}

// ---------------- bf16 GEMM: C = relu(A[M,K] @ Bt[N,K]^T + bias), C bf16 [M,N] ----------------
// 128x128 tile, BK=32, 256 threads (4 waves, 2x2), 16x16x32 MFMA, global_load_lds staging.
__global__ __launch_bounds__(256) void gemm_bt_relu(const __bf16* __restrict__ Ag,
                                                    const __bf16* __restrict__ Btg,
                                                    const float* __restrict__ bias,
                                                    __bf16* __restrict__ Cg,
                                                    int M, int N, int K) {
    __shared__ alignas(16) __bf16 As[128 * 32];
    __shared__ alignas(16) __bf16 Bs[128 * 32];
    const int tid = threadIdx.x;
    const int wave = tid >> 6, lane = tid & 63;
    const int bm = blockIdx.x, bn = blockIdx.y;
    const int wm = wave >> 1, wn = wave & 1;

    // staging: chunk = 16B unit; row = chunk>>2 (64B/row), k-offset = (chunk&3)*8 elems
    const int chunk0 = wave * 128 + lane;
    const int chunk1 = chunk0 + 64;
    const int rowA0 = chunk0 >> 2, kO0 = (chunk0 & 3) * 8;
    const int rowA1 = chunk1 >> 2, kO1 = (chunk1 & 3) * 8;
    const __bf16* aSrc0 = Ag + (size_t)(bm * 128 + rowA0) * K + kO0;
    const __bf16* aSrc1 = Ag + (size_t)(bm * 128 + rowA1) * K + kO1;
    const __bf16* bSrc0 = Btg + (size_t)(bn * 128 + rowA0) * K + kO0;
    const __bf16* bSrc1 = Btg + (size_t)(bn * 128 + rowA1) * K + kO1;
    __bf16* aDst0 = As + wave * 1024;
    __bf16* aDst1 = As + wave * 1024 + 512;
    __bf16* bDst0 = Bs + wave * 1024;
    __bf16* bDst1 = Bs + wave * 1024 + 512;

    f32x4 acc[4][4] = {};
    const int frRow = lane & 15;
    const int frK = (lane >> 4) * 8;

    for (int k0 = 0; k0 < K; k0 += 32) {
        gld16(aSrc0 + k0, aDst0);
        gld16(aSrc1 + k0, aDst1);
        gld16(bSrc0 + k0, bDst0);
        gld16(bSrc1 + k0, bDst1);
        __syncthreads();
        bf16x8 af[4], bfr[4];
#pragma unroll
        for (int m = 0; m < 4; m++)
            af[m] = *(const bf16x8*)&As[(wm * 64 + m * 16 + frRow) * 32 + frK];
#pragma unroll
        for (int n = 0; n < 4; n++)
            bfr[n] = *(const bf16x8*)&Bs[(wn * 64 + n * 16 + frRow) * 32 + frK];
#pragma unroll
        for (int m = 0; m < 4; m++)
#pragma unroll
            for (int n = 0; n < 4; n++)
                acc[m][n] = __builtin_amdgcn_mfma_f32_16x16x32_bf16(af[m], bfr[n], acc[m][n], 0, 0, 0);
        __syncthreads();
    }

    // epilogue: C/D layout col = lane&15, row = (lane>>4)*4 + reg
    const int c0 = lane & 15, r0 = (lane >> 4) * 4;
#pragma unroll
    for (int n = 0; n < 4; n++) {
        const int colG = bn * 128 + wn * 64 + n * 16 + c0;
        const float bv = bias[colG];
#pragma unroll
        for (int m = 0; m < 4; m++) {
            const int rowG = bm * 128 + wm * 64 + m * 16 + r0;
#pragma unroll
            for (int r = 0; r < 4; r++) {
                float v = acc[m][n][r] + bv;
                v = fmaxf(v, 0.0f);
                Cg[(size_t)(rowG + r) * N + colG] = (__bf16)v;
            }
        }
    }
}

// ---------------- head: out[b,j] = h2[b,:] . Wq3[:,j] + bq3[j], j<3, K=512 ----------------
__global__ __launch_bounds__(256) void head_kernel(const __bf16* __restrict__ h2,
                                                   const float* __restrict__ Wq3,
                                                   const float* __restrict__ bq3,
                                                   float* __restrict__ out) {
    const int wave = threadIdx.x >> 6, lane = threadIdx.x & 63;
    const int row = blockIdx.x * 4 + wave;
    const bf16x8 hv = *(const bf16x8*)(h2 + (size_t)row * 512 + lane * 8);
    float s0 = 0.f, s1 = 0.f, s2 = 0.f;
#pragma unroll
    for (int i = 0; i < 8; i++) {
        const float hf = (float)hv[i];
        const int k = lane * 8 + i;
        s0 += hf * Wq3[k * 3 + 0];
        s1 += hf * Wq3[k * 3 + 1];
        s2 += hf * Wq3[k * 3 + 2];
    }
#pragma unroll
    for (int off = 32; off > 0; off >>= 1) {
        s0 += __shfl_xor(s0, off);
        s1 += __shfl_xor(s1, off);
        s2 += __shfl_xor(s2, off);
    }
    if (lane == 0) {
        float* o = out + (size_t)row * 3;
        o[0] = s0 + bq3[0];
        o[1] = s1 + bq3[1];
        o[2] = s2 + bq3[2];
    }
}

extern "C" void kernel_launch(void* const* d_in, const int* in_sizes, int n_in,
                              void* d_out, int out_size, void* d_ws, size_t ws_size,
                              hipStream_t stream) {
    const float* obs = (const float*)d_in[0];
    const float* act = (const float*)d_in[1];
    const float* Wp1 = (const float*)d_in[2];  const float* bp1 = (const float*)d_in[3];
    const float* Wp2 = (const float*)d_in[4];  const float* bp2 = (const float*)d_in[5];
    const float* Wt1 = (const float*)d_in[6];  const float* bt1 = (const float*)d_in[7];
    const float* Wt2 = (const float*)d_in[8];  const float* bt2 = (const float*)d_in[9];
    const float* Wr1 = (const float*)d_in[10]; const float* br1 = (const float*)d_in[11];
    const float* Wr2 = (const float*)d_in[12]; const float* br2 = (const float*)d_in[13];
    const float* Wq1 = (const float*)d_in[14]; const float* bq1 = (const float*)d_in[15];
    const float* Wq2 = (const float*)d_in[16]; const float* bq2 = (const float*)d_in[17];
    const float* Wq3 = (const float*)d_in[18]; const float* bq3 = (const float*)d_in[19];
    float* out = (float*)d_out;

    char* ws = (char*)d_ws;
    __bf16* enc = (__bf16*)(ws);                            // 16384*2688*2 = 88,080,384
    __bf16* h1  = (__bf16*)(ws + 88080384);                 // 16384*1024*2 = 33,554,432
    __bf16* h2  = (__bf16*)(ws + 88080384 + 33554432);      // 16384*512*2  = 16,777,216
    __bf16* w1t = (__bf16*)(ws + 138412032);                // 1024*2688*2  = 5,505,024
    __bf16* w2t = (__bf16*)(ws + 143917056);                // 512*1024*2   = 1,048,576

    // weight transposes (f32 -> bf16, [K,N] -> [N,K])
    transpose_bf16_k<<<dim3(2688 / 64, 1024 / 64), 256, 0, stream>>>(Wq1, w1t, 2688, 1024);
    transpose_bf16_k<<<dim3(1024 / 64, 512 / 64), 256, 0, stream>>>(Wq2, w2t, 1024, 512);

    // encoders: 49152 rows, 256 rows/block
    enc_kernel<5, 0><<<dim3(192, 9), 256, 0, stream>>>(obs, act, Wp1, bp1, Wp2, bp2, enc, 0, 0);
    enc_kernel<12, 1><<<dim3(192, 2), 256, 0, stream>>>(obs, act, Wt1, bt1, Wt2, bt2, enc, 9, 18);
    enc_kernel<9, 2><<<dim3(192, 3), 256, 0, stream>>>(obs, act, Wr1, br1, Wr2, br2, enc, 11, 117);

    // q head
    gemm_bt_relu<<<dim3(16384 / 128, 1024 / 128), 256, 0, stream>>>(enc, w1t, bq1, h1, 16384, 1024, 2688);
    gemm_bt_relu<<<dim3(16384 / 128, 512 / 128), 256, 0, stream>>>(h1, w2t, bq2, h2, 16384, 512, 1024);
    head_kernel<<<16384 / 4, 256, 0, stream>>>(h2, Wq3, bq3, out);
}

// Round 2
// 245.226 us; speedup vs baseline: 1.2373x; 1.2373x over previous
//
#include <hip/hip_runtime.h>
#include <hip/hip_bf16.h>
#include <cstdint>

typedef __bf16 bf16x8 __attribute__((ext_vector_type(8)));
typedef float f32x4 __attribute__((ext_vector_type(4)));

// ---------------- async global->LDS (16B per lane) ----------------
__device__ __forceinline__ void gld16(const __bf16* g, __bf16* lds) {
    __builtin_amdgcn_global_load_lds(
        (__attribute__((address_space(1))) void*)(uintptr_t)g,
        (__attribute__((address_space(3))) void*)(uint32_t)(uintptr_t)lds,
        16, 0, 0);
}

// ---------------- transpose + f32->bf16 convert: out[C][R] = in[R][C] ----------------
__global__ __launch_bounds__(256) void transpose_bf16_k(const float* __restrict__ in,
                                                        __bf16* __restrict__ out,
                                                        int R, int C) {
    __shared__ float t[64][65];
    const int r0 = blockIdx.x * 64, c0 = blockIdx.y * 64;
    const int tid = threadIdx.x;
#pragma unroll
    for (int i = 0; i < 16; i++) {
        int idx = i * 256 + tid;
        int rr = idx >> 6, cc = idx & 63;
        t[rr][cc] = in[(size_t)(r0 + rr) * C + (c0 + cc)];
    }
    __syncthreads();
#pragma unroll
    for (int i = 0; i < 16; i++) {
        int idx = i * 256 + tid;
        int rr = idx >> 6, cc = idx & 63;
        out[(size_t)(c0 + rr) * R + (r0 + cc)] = (__bf16)t[cc][rr];
    }
}

// ---------------- encoder: per (row, segment) 2-layer MLP ----------------
template <int DIN, int MODE>
__global__ __launch_bounds__(256) void enc_kernel(const float* __restrict__ obs,
                                                  const float* __restrict__ act,
                                                  const float* __restrict__ W1g,
                                                  const float* __restrict__ b1g,
                                                  const float* __restrict__ W2g,
                                                  const float* __restrict__ b2g,
                                                  __bf16* __restrict__ enc,
                                                  int kgBase, int xBase) {
    const int k = blockIdx.y;
    const int kg = kgBase + k;
    __shared__ float sW1[DIN * 32];
    __shared__ float sW2[32 * 64];
    __shared__ float sb1[32];
    __shared__ float sb2[64];
    const int tid = threadIdx.x;
    for (int i = tid; i < DIN * 32; i += 256) sW1[i] = W1g[k * DIN * 32 + i];
    for (int i = tid; i < 2048; i += 256) sW2[i] = W2g[k * 2048 + i];
    if (tid < 32) sb1[tid] = b1g[k * 32 + tid];
    else if (tid < 96) sb2[tid - 32] = b2g[k * 64 + (tid - 32)];
    __syncthreads();

    const int r = blockIdx.x * 256 + tid;
    const float* orow = obs + (size_t)r * 144;
    float x[DIN];
    if (MODE == 0) {
        x[0] = orow[2 * k];
        x[1] = orow[2 * k + 1];
        const float* arow = act + (size_t)r * 3;
        x[2] = arow[0]; x[3] = arow[1]; x[4] = arow[2];
    } else {
#pragma unroll
        for (int i = 0; i < DIN; i++) x[i] = orow[xBase + DIN * k + i];
    }

    float h[32];
#pragma unroll
    for (int o = 0; o < 32; o++) {
        float a = sb1[o];
#pragma unroll
        for (int i = 0; i < DIN; i++) a += x[i] * sW1[i * 32 + o];
        h[o] = fmaxf(a, 0.01f * a);
    }

    __bf16* dst = enc + (size_t)r * 896 + kg * 64;
#pragma unroll
    for (int og = 0; og < 8; og++) {
        bf16x8 tmp;
#pragma unroll
        for (int oi = 0; oi < 8; oi++) {
            const int o = og * 8 + oi;
            float a = sb2[o];
#pragma unroll
            for (int hh = 0; hh < 32; hh++) a += h[hh] * sW2[hh * 64 + o];
            a = fmaxf(a, 0.01f * a);
            tmp[oi] = (__bf16)a;
        }
        *(bf16x8*)&dst[og * 8] = tmp;
    }
}

// ---------------- 256x256 8-phase bf16 GEMM: C = relu(A[M,K] @ Bt[N,K]^T + bias) ----------------
// 8 waves (2M x 4N), BK=64, double-buffered 128KiB LDS, XOR-swizzled (both-sides),
// counted vmcnt, setprio around MFMA clusters, XCD-swizzled block id.
__global__ __launch_bounds__(512, 2) void gemm256_relu(const __bf16* __restrict__ Ag,
                                                       const __bf16* __restrict__ Btg,
                                                       const float* __restrict__ bias,
                                                       __bf16* __restrict__ Cg,
                                                       int M, int N, int K,
                                                       int nbm, int nbn) {
    // lds[buf][A=0/B=1][half][128*64]
    __shared__ __align__(16) __bf16 lds[2][2][2][128 * 64];
    const int tid = threadIdx.x;
    const int wid = tid >> 6, lane = tid & 63;
    const int wm = wid >> 2, wn = wid & 3;
    const int fr = lane & 15, kq = lane >> 4;

    // XCD-aware bijective swizzle (nwg % 8 == 0 by construction)
    const int nwg = nbm * nbn;
    const int chunk = nwg >> 3;
    const int wg = (blockIdx.x & 7) * chunk + (blockIdx.x >> 3);
    const int bn = wg / nbm, bm = wg % nbm;

    // ---- staging source pointers (pre-swizzled so LDS dest stays linear) ----
    // chunk c in [0,1024): row=c>>3, slot=c&7; data for (row,slot) comes from src slot^(row&7)
    const int c0 = tid, c1 = tid + 512;
    const int r0 = c0 >> 3, s0 = (c0 & 7) ^ (r0 & 7);
    const int r1 = c1 >> 3, s1 = (c1 & 7) ^ (r1 & 7);
    const __bf16* aS[2][2];
    const __bf16* bS[2][2];
#pragma unroll
    for (int h = 0; h < 2; h++) {
        aS[h][0] = Ag + (size_t)(bm * 256 + h * 128 + r0) * K + s0 * 8;
        aS[h][1] = Ag + (size_t)(bm * 256 + h * 128 + r1) * K + s1 * 8;
        bS[h][0] = Btg + (size_t)(bn * 256 + h * 128 + r0) * K + s0 * 8;
        bS[h][1] = Btg + (size_t)(bn * 256 + h * 128 + r1) * K + s1 * 8;
    }

    f32x4 acc[2][2][4][2] = {};
    bf16x8 af[4][2], bfr[2][2];

#define STAGE(BUF, AB, H, KO)                                         \
    do {                                                              \
        __bf16* d_ = &lds[BUF][AB][H][0];                             \
        const __bf16* g0_ = (AB) ? bS[H][0] : aS[H][0];               \
        const __bf16* g1_ = (AB) ? bS[H][1] : aS[H][1];               \
        gld16(g0_ + (KO), d_ + c0 * 8);                               \
        gld16(g1_ + (KO), d_ + c1 * 8);                               \
    } while (0)

    // swizzled fragment read: row*128B rows, 8 slots of 16B, slot ^= (row&7)
#define LDF(BUF, AB, H, ROW, KS) \
    (*(const bf16x8*)&lds[BUF][AB][H][(ROW) * 64 + (((KS)*4 + kq) ^ ((ROW)&7)) * 8])

#define LOAD_A(BUF, H)                                                \
    _Pragma("unroll") for (int m = 0; m < 4; m++)                     \
        _Pragma("unroll") for (int ks = 0; ks < 2; ks++)              \
            af[m][ks] = LDF(BUF, 0, H, wm * 64 + m * 16 + fr, ks);

#define LOAD_B(BUF, H)                                                \
    _Pragma("unroll") for (int n = 0; n < 2; n++)                     \
        _Pragma("unroll") for (int ks = 0; ks < 2; ks++)              \
            bfr[n][ks] = LDF(BUF, 1, H, wn * 32 + n * 16 + fr, ks);

#define MFMA_Q(Q, R)                                                  \
    __builtin_amdgcn_s_barrier();                                     \
    asm volatile("s_waitcnt lgkmcnt(0)" ::: "memory");                \
    __builtin_amdgcn_sched_barrier(0);                                \
    __builtin_amdgcn_s_setprio(1);                                    \
    _Pragma("unroll") for (int ks = 0; ks < 2; ks++)                  \
        _Pragma("unroll") for (int m = 0; m < 4; m++)                 \
            _Pragma("unroll") for (int n = 0; n < 2; n++)             \
                acc[Q][R][m][n] = __builtin_amdgcn_mfma_f32_16x16x32_bf16( \
                    af[m][ks], bfr[n][ks], acc[Q][R][m][n], 0, 0, 0); \
    __builtin_amdgcn_s_setprio(0);

    const int NT = K >> 6;

    // prologue: stage K-tile 0 into buf 0, full drain once
    STAGE(0, 0, 0, 0);
    STAGE(0, 0, 1, 0);
    STAGE(0, 1, 0, 0);
    STAGE(0, 1, 1, 0);
    asm volatile("s_waitcnt vmcnt(0)" ::: "memory");
    __builtin_amdgcn_s_barrier();

    for (int t = 0; t < NT; ++t) {
        const int buf = t & 1, nb = buf ^ 1;
        const int kO = (t + 1) << 6;
        const bool st = (t + 1 < NT);

        // phase 1: quadrant (0,0) — needs A0,B0; stage A0 of next tile
        LOAD_A(buf, 0)
        LOAD_B(buf, 0)
        if (st) STAGE(nb, 0, 0, kO);
        MFMA_Q(0, 0)
        asm volatile("s_waitcnt vmcnt(4)" ::: "memory");
        __builtin_amdgcn_s_barrier();

        // phase 2: quadrant (0,1) — reuse A, load B1; stage B0 of next tile
        LOAD_B(buf, 1)
        if (st) STAGE(nb, 1, 0, kO);
        MFMA_Q(0, 1)
        asm volatile("s_waitcnt vmcnt(4)" ::: "memory");
        __builtin_amdgcn_s_barrier();

        // phase 3: quadrant (1,1) — load A1, reuse B; stage B1 of next tile
        LOAD_A(buf, 1)
        if (st) STAGE(nb, 1, 1, kO);
        MFMA_Q(1, 1)
        __builtin_amdgcn_s_barrier();

        // phase 4: quadrant (1,0) — reuse A, reload B0; stage A1 of next tile
        LOAD_B(buf, 0)
        if (st) STAGE(nb, 0, 1, kO);
        MFMA_Q(1, 0)
        asm volatile("s_waitcnt vmcnt(4)" ::: "memory");
        __builtin_amdgcn_s_barrier();
    }

    // epilogue: C/D layout col=lane&15, row=(lane>>4)*4+reg
    const int cc = lane & 15, rr = (lane >> 4) << 2;
#pragma unroll
    for (int q = 0; q < 2; q++)
#pragma unroll
        for (int r2 = 0; r2 < 2; r2++)
#pragma unroll
            for (int m = 0; m < 4; m++)
#pragma unroll
                for (int n = 0; n < 2; n++) {
                    const int colG = bn * 256 + r2 * 128 + wn * 32 + n * 16 + cc;
                    const int rowG = bm * 256 + q * 128 + wm * 64 + m * 16 + rr;
                    const float bv = bias[colG];
#pragma unroll
                    for (int reg = 0; reg < 4; reg++) {
                        float v = acc[q][r2][m][n][reg] + bv;
                        v = fmaxf(v, 0.0f);
                        Cg[(size_t)(rowG + reg) * N + colG] = (__bf16)v;
                    }
                }
#undef STAGE
#undef LDF
#undef LOAD_A
#undef LOAD_B
#undef MFMA_Q
}

// ---------------- head: out[b,j] = h2[b,:] . Wq3[:,j] + bq3[j], j<3, K=512 ----------------
__global__ __launch_bounds__(256) void head_kernel(const __bf16* __restrict__ h2,
                                                   const float* __restrict__ Wq3,
                                                   const float* __restrict__ bq3,
                                                   float* __restrict__ out) {
    const int wave = threadIdx.x >> 6, lane = threadIdx.x & 63;
    const int row = blockIdx.x * 4 + wave;
    const bf16x8 hv = *(const bf16x8*)(h2 + (size_t)row * 512 + lane * 8);
    float s0 = 0.f, s1 = 0.f, s2 = 0.f;
#pragma unroll
    for (int i = 0; i < 8; i++) {
        const float hf = (float)hv[i];
        const int k = lane * 8 + i;
        s0 += hf * Wq3[k * 3 + 0];
        s1 += hf * Wq3[k * 3 + 1];
        s2 += hf * Wq3[k * 3 + 2];
    }
#pragma unroll
    for (int off = 32; off > 0; off >>= 1) {
        s0 += __shfl_xor(s0, off);
        s1 += __shfl_xor(s1, off);
        s2 += __shfl_xor(s2, off);
    }
    if (lane == 0) {
        float* o = out + (size_t)row * 3;
        o[0] = s0 + bq3[0];
        o[1] = s1 + bq3[1];
        o[2] = s2 + bq3[2];
    }
}

extern "C" void kernel_launch(void* const* d_in, const int* in_sizes, int n_in,
                              void* d_out, int out_size, void* d_ws, size_t ws_size,
                              hipStream_t stream) {
    const float* obs = (const float*)d_in[0];
    const float* act = (const float*)d_in[1];
    const float* Wp1 = (const float*)d_in[2];  const float* bp1 = (const float*)d_in[3];
    const float* Wp2 = (const float*)d_in[4];  const float* bp2 = (const float*)d_in[5];
    const float* Wt1 = (const float*)d_in[6];  const float* bt1 = (const float*)d_in[7];
    const float* Wt2 = (const float*)d_in[8];  const float* bt2 = (const float*)d_in[9];
    const float* Wr1 = (const float*)d_in[10]; const float* br1 = (const float*)d_in[11];
    const float* Wr2 = (const float*)d_in[12]; const float* br2 = (const float*)d_in[13];
    const float* Wq1 = (const float*)d_in[14]; const float* bq1 = (const float*)d_in[15];
    const float* Wq2 = (const float*)d_in[16]; const float* bq2 = (const float*)d_in[17];
    const float* Wq3 = (const float*)d_in[18]; const float* bq3 = (const float*)d_in[19];
    float* out = (float*)d_out;

    char* ws = (char*)d_ws;
    __bf16* enc = (__bf16*)(ws);                            // 16384*2688*2 = 88,080,384
    __bf16* h1  = (__bf16*)(ws + 88080384);                 // 16384*1024*2 = 33,554,432
    __bf16* h2  = (__bf16*)(ws + 88080384 + 33554432);      // 16384*512*2  = 16,777,216
    __bf16* w1t = (__bf16*)(ws + 138412032);                // 1024*2688*2  = 5,505,024
    __bf16* w2t = (__bf16*)(ws + 143917056);                // 512*1024*2   = 1,048,576

    // weight transposes (f32 -> bf16, [K,N] -> [N,K])
    transpose_bf16_k<<<dim3(2688 / 64, 1024 / 64), 256, 0, stream>>>(Wq1, w1t, 2688, 1024);
    transpose_bf16_k<<<dim3(1024 / 64, 512 / 64), 256, 0, stream>>>(Wq2, w2t, 1024, 512);

    // encoders: 49152 rows, 256 rows/block
    enc_kernel<5, 0><<<dim3(192, 9), 256, 0, stream>>>(obs, act, Wp1, bp1, Wp2, bp2, enc, 0, 0);
    enc_kernel<12, 1><<<dim3(192, 2), 256, 0, stream>>>(obs, act, Wt1, bt1, Wt2, bt2, enc, 9, 18);
    enc_kernel<9, 2><<<dim3(192, 3), 256, 0, stream>>>(obs, act, Wr1, br1, Wr2, br2, enc, 11, 117);

    // q head: 256x256 8-phase MFMA GEMMs
    gemm256_relu<<<dim3(64 * 4), 512, 0, stream>>>(enc, w1t, bq1, h1, 16384, 1024, 2688, 64, 4);
    gemm256_relu<<<dim3(64 * 2), 512, 0, stream>>>(h1, w2t, bq2, h2, 16384, 512, 1024, 64, 2);
    head_kernel<<<16384 / 4, 256, 0, stream>>>(h2, Wq3, bq3, out);
}